// Round 7
// baseline (1736.731 us; speedup 1.0000x reference)
//
#include <hip/hip_runtime.h>
#include <cstdint>

// ---- bf16 pack/unpack helpers (RNE) ----
__device__ inline unsigned int bfpack2(float a, float b) {
  unsigned int ua = __float_as_uint(a), ub = __float_as_uint(b);
  ua += 0x7FFFu + ((ua >> 16) & 1u);
  ub += 0x7FFFu + ((ub >> 16) & 1u);
  return (ua >> 16) | (ub & 0xFFFF0000u);
}
__device__ inline float bflo(unsigned int u) { return __uint_as_float(u << 16); }
__device__ inline float bfhi(unsigned int u) { return __uint_as_float(u & 0xFFFF0000u); }

// ---------------- degree histograms ----------------
__global__ __launch_bounds__(256) void pre_kernel(const int* __restrict__ src,
                                                  const int* __restrict__ dst,
                                                  int* __restrict__ deg,
                                                  int* __restrict__ deg2, int nE) {
  int e = blockIdx.x * 256 + threadIdx.x;
  if (e < nE) {
    atomicAdd(&deg[dst[e]], 1);
    atomicAdd(&deg2[src[e]], 1);
  }
}

// ---------------- scan stage A: per-block scan of BOTH deg arrays ----------------
// blocks [0,nb): deg (8-pad rounding) -> rp/part ; blocks [nb,2nb): deg2 -> rp2/part2
__global__ __launch_bounds__(256) void scanA_kernel(const int* __restrict__ deg,
                                                    const int* __restrict__ deg2,
                                                    int* __restrict__ rp,
                                                    int* __restrict__ rp2,
                                                    int* __restrict__ part,
                                                    int* __restrict__ part2,
                                                    int n, int nb) {
  __shared__ int sh[256];
  int b = blockIdx.x, t = threadIdx.x;
  const int* d = (b < nb) ? deg : deg2;
  int* r = (b < nb) ? rp : rp2;
  int* p = (b < nb) ? part : part2;
  int pad = (b < nb) ? 1 : 0;
  int bb = (b < nb) ? b : b - nb;
  int base = bb * 1024 + t * 4;
  int v0 = (base + 0 < n) ? d[base + 0] : 0;
  int v1 = (base + 1 < n) ? d[base + 1] : 0;
  int v2 = (base + 2 < n) ? d[base + 2] : 0;
  int v3 = (base + 3 < n) ? d[base + 3] : 0;
  if (pad) {
    v0 = (v0 + 7) & ~7; v1 = (v1 + 7) & ~7;
    v2 = (v2 + 7) & ~7; v3 = (v3 + 7) & ~7;
  }
  int ts = v0 + v1 + v2 + v3;
  sh[t] = ts;
  __syncthreads();
  for (int off = 1; off < 256; off <<= 1) {
    int x = (t >= off) ? sh[t - off] : 0;
    __syncthreads();
    sh[t] += x;
    __syncthreads();
  }
  int excl = sh[t] - ts;
  if (t == 255) p[bb] = sh[255];
  if (base + 0 < n) r[base + 0] = excl;
  if (base + 1 < n) r[base + 1] = excl + v0;
  if (base + 2 < n) r[base + 2] = excl + v0 + v1;
  if (base + 3 < n) r[base + 3] = excl + v0 + v1 + v2;
}

// ---------------- scan stage B: serial scan of both partial arrays ----------------
__global__ void scanB_kernel(int* part, int* part2, int* rp, int* rp2, int nb, int n) {
  if (threadIdx.x == 0) {
    int* p = (blockIdx.x == 0) ? part : part2;
    int* r = (blockIdx.x == 0) ? rp : rp2;
    int run = 0;
    for (int i = 0; i < nb; ++i) { int v = p[i]; p[i] = run; run += v; }
    r[n] = run;
  }
}

// ---------------- scan stage C: finalize rp/rp2, init cursors, dinv ----------------
__global__ __launch_bounds__(256) void scanC_kernel(int* __restrict__ rp,
                                                    int* __restrict__ rp2,
                                                    const int* __restrict__ part,
                                                    const int* __restrict__ part2,
                                                    int* __restrict__ cursor,
                                                    int* __restrict__ cursor2,
                                                    const int* __restrict__ deg,
                                                    float* __restrict__ dinv, int n) {
  int i = blockIdx.x * 256 + threadIdx.x;
  if (i < n) {
    int v = rp[i] + part[i >> 10];
    rp[i] = v;
    cursor[i] = v;
    dinv[i] = rsqrtf((float)deg[i] + 1.0f);
  } else if (i < 2 * n) {
    int j = i - n;
    int v = rp2[j] + part2[j >> 10];
    rp2[j] = v;
    cursor2[j] = v;
  }
}

// ---------------- place + pad fused ----------------
// t < E: CSR placement (swv = interleaved {src, wgt} int2, single 8B store) +
//        src-ordered packed edge list. t >= E: fill pad slots with w=0.
__global__ __launch_bounds__(256) void placepad_kernel(const int* __restrict__ src,
                                                       const int* __restrict__ dst,
                                                       const int* __restrict__ batch,
                                                       const float* __restrict__ dinv,
                                                       int* __restrict__ cursor,
                                                       int* __restrict__ cursor2,
                                                       int2* __restrict__ swv,
                                                       unsigned int* __restrict__ epk,
                                                       const int* __restrict__ rp,
                                                       const int* __restrict__ deg,
                                                       int nE, int nN) {
  int t = blockIdx.x * 256 + threadIdx.x;
  if (t < nE) {
    int s = src[t];
    int d = dst[t];
    int p1 = atomicAdd(&cursor[d], 1);
    int2 sw; sw.x = s; sw.y = __float_as_int(dinv[s] * dinv[d]);
    swv[p1] = sw;
    int g = batch[s];
    int p2 = atomicAdd(&cursor2[s], 1);
    epk[p2] = ((unsigned int)g << 21) | (unsigned int)t;
  } else if (t < nE + nN) {
    int i = t - nE;
    int b = rp[i] + deg[i], e = rp[i + 1];
    int2 z; z.x = i; z.y = 0;
    for (int k = b; k < e; ++k) swv[k] = z;
  }
}

// ---------------- dense GEMM: hpk[N,64] = pack_bf16(act(A)[N,128] @ W[128,128]) ----------------
template <bool FUSED>
__global__ __launch_bounds__(256) void gemm128_kernel(const float* __restrict__ A,
                                                      const float* __restrict__ W,
                                                      const float* __restrict__ scale,
                                                      const float* __restrict__ shift,
                                                      unsigned int* __restrict__ hpk,
                                                      int nrows) {
  extern __shared__ float lds[];
  float* Ws = lds;             // 128*128 floats
  float* xs = lds + 128 * 128; // 16*128 floats
  const int t = threadIdx.x;
  for (int i = t; i < (128 * 128) / 4; i += 256)
    reinterpret_cast<float4*>(Ws)[i] = reinterpret_cast<const float4*>(W)[i];
  const int wave = t >> 6, lane = t & 63;
  for (int rb = blockIdx.x * 16; rb < nrows; rb += gridDim.x * 16) {
    int nr = min(16, nrows - rb);
    __syncthreads();
    for (int i = t; i < nr * 32; i += 256) {
      float4 v = reinterpret_cast<const float4*>(A + (size_t)rb * 128)[i];
      if (FUSED) {
        float4 sc4 = reinterpret_cast<const float4*>(scale)[i & 31];
        float4 sh4 = reinterpret_cast<const float4*>(shift)[i & 31];
        v.x = fmaxf(fmaf(v.x, sc4.x, sh4.x), 0.f);
        v.y = fmaxf(fmaf(v.y, sc4.y, sh4.y), 0.f);
        v.z = fmaxf(fmaf(v.z, sc4.z, sh4.z), 0.f);
        v.w = fmaxf(fmaf(v.w, sc4.w, sh4.w), 0.f);
      }
      reinterpret_cast<float4*>(xs)[i] = v;
    }
    __syncthreads();
    float acc[4][2] = {{0.f, 0.f}, {0.f, 0.f}, {0.f, 0.f}, {0.f, 0.f}};
    const float* xw = xs + wave * 4 * 128;
#pragma unroll 4
    for (int k = 0; k < 128; ++k) {
      float w0 = Ws[k * 128 + lane];
      float w1 = Ws[k * 128 + 64 + lane];
#pragma unroll
      for (int r = 0; r < 4; ++r) {
        float a = xw[r * 128 + k];
        acc[r][0] = fmaf(a, w0, acc[r][0]);
        acc[r][1] = fmaf(a, w1, acc[r][1]);
      }
    }
#pragma unroll
    for (int r = 0; r < 4; ++r) {
      int row = rb + wave * 4 + r;
      if (row < nrows)
        hpk[(size_t)row * 64 + lane] = bfpack2(acc[r][0], acc[r][1]);
    }
  }
}

// ---------------- edge MLP body (graph-sorted run-length; lane = ch l, 64+l) ----------------
__device__ __forceinline__ void edge_body(const float* __restrict__ ea,
                                          const unsigned int* __restrict__ epk,
                                          const float* __restrict__ We1,
                                          const float* __restrict__ be1,
                                          float* __restrict__ esum,
                                          float* __restrict__ ecnt,
                                          int nE, int chunk) {
  const int lane = threadIdx.x & 63;
  const int wid = (blockIdx.x * 256 + threadIdx.x) >> 6;
  int beg = wid * chunk;
  if (beg >= nE) return;
  int end = min(nE, beg + chunk);
  float w0[16], w1[16];
#pragma unroll
  for (int k = 0; k < 16; ++k) {
    w0[k] = We1[k * 128 + lane];
    w1[k] = We1[k * 128 + 64 + lane];
  }
  float b0 = be1[lane], b1 = be1[64 + lane];
  int cur = -1;
  float a0 = 0.f, a1 = 0.f, cnt = 0.f;
  for (int j = beg; j < end; ++j) {
    unsigned int pk = epk[j];
    int g = (int)(pk >> 21);
    int e = (int)(pk & 0x1FFFFFu);
    if (g != cur) {
      if (cur >= 0) {
        atomicAdd(&esum[cur * 128 + lane], a0);
        atomicAdd(&esum[cur * 128 + 64 + lane], a1);
        if (lane == 0) atomicAdd(&ecnt[cur], cnt);
      }
      cur = g; a0 = 0.f; a1 = 0.f; cnt = 0.f;
    }
    const float4* eap = reinterpret_cast<const float4*>(ea + (size_t)e * 16);
    float4 t0 = eap[0], t1 = eap[1], t2 = eap[2], t3 = eap[3];
    float u0 = b0, u1 = b1;
    u0 = fmaf(t0.x, w0[0], u0);  u1 = fmaf(t0.x, w1[0], u1);
    u0 = fmaf(t0.y, w0[1], u0);  u1 = fmaf(t0.y, w1[1], u1);
    u0 = fmaf(t0.z, w0[2], u0);  u1 = fmaf(t0.z, w1[2], u1);
    u0 = fmaf(t0.w, w0[3], u0);  u1 = fmaf(t0.w, w1[3], u1);
    u0 = fmaf(t1.x, w0[4], u0);  u1 = fmaf(t1.x, w1[4], u1);
    u0 = fmaf(t1.y, w0[5], u0);  u1 = fmaf(t1.y, w1[5], u1);
    u0 = fmaf(t1.z, w0[6], u0);  u1 = fmaf(t1.z, w1[6], u1);
    u0 = fmaf(t1.w, w0[7], u0);  u1 = fmaf(t1.w, w1[7], u1);
    u0 = fmaf(t2.x, w0[8], u0);  u1 = fmaf(t2.x, w1[8], u1);
    u0 = fmaf(t2.y, w0[9], u0);  u1 = fmaf(t2.y, w1[9], u1);
    u0 = fmaf(t2.z, w0[10], u0); u1 = fmaf(t2.z, w1[10], u1);
    u0 = fmaf(t2.w, w0[11], u0); u1 = fmaf(t2.w, w1[11], u1);
    u0 = fmaf(t3.x, w0[12], u0); u1 = fmaf(t3.x, w1[12], u1);
    u0 = fmaf(t3.y, w0[13], u0); u1 = fmaf(t3.y, w1[13], u1);
    u0 = fmaf(t3.z, w0[14], u0); u1 = fmaf(t3.z, w1[14], u1);
    u0 = fmaf(t3.w, w0[15], u0); u1 = fmaf(t3.w, w1[15], u1);
    a0 += fmaxf(u0, 0.f);
    a1 += fmaxf(u1, 0.f);
    cnt += 1.f;
  }
  if (cur >= 0) {
    atomicAdd(&esum[cur * 128 + lane], a0);
    atomicAdd(&esum[cur * 128 + 64 + lane], a1);
    if (lane == 0) atomicAdd(&ecnt[cur], cnt);
  }
}

// ---------------- SpMM body (wave/node, 8 independent row-gathers in flight) ----------------
__device__ __forceinline__ void spmm_body(const unsigned int* __restrict__ hpk,
                                          const float* __restrict__ dinv,
                                          const int* __restrict__ rp,
                                          const int2* __restrict__ swv,
                                          const float* __restrict__ bias,
                                          float* __restrict__ outp,
                                          float* __restrict__ bnsum,
                                          float* __restrict__ bnsq, int nN, int eb) {
  const int lane = threadIdx.x & 63;
  const int wid = ((blockIdx.x - eb) * 256 + threadIdx.x) >> 6;
  const int nw = (gridDim.x - eb) * 4;
  float b0 = bias[lane], b1 = bias[64 + lane];
  float s0 = 0.f, s1 = 0.f, q0 = 0.f, q1 = 0.f;
  for (int n = wid; n < nN; n += nw) {
    const int beg = rp[n], end = rp[n + 1];
    float aA0 = 0.f, aA1 = 0.f, aB0 = 0.f, aB1 = 0.f;
    for (int j = beg; j < end; j += 8) {
      const int4* q = reinterpret_cast<const int4*>(swv + j);
      int4 A = q[0], B = q[1], C = q[2], D = q[3];
      unsigned int p0 = hpk[(size_t)A.x * 64 + lane];
      unsigned int p1 = hpk[(size_t)A.z * 64 + lane];
      unsigned int p2 = hpk[(size_t)B.x * 64 + lane];
      unsigned int p3 = hpk[(size_t)B.z * 64 + lane];
      unsigned int p4 = hpk[(size_t)C.x * 64 + lane];
      unsigned int p5 = hpk[(size_t)C.z * 64 + lane];
      unsigned int p6 = hpk[(size_t)D.x * 64 + lane];
      unsigned int p7 = hpk[(size_t)D.z * 64 + lane];
      float w0 = __int_as_float(A.y), w1 = __int_as_float(A.w);
      float w2 = __int_as_float(B.y), w3 = __int_as_float(B.w);
      float w4 = __int_as_float(C.y), w5 = __int_as_float(C.w);
      float w6 = __int_as_float(D.y), w7 = __int_as_float(D.w);
      aA0 = fmaf(w0, bflo(p0), aA0); aA1 = fmaf(w0, bfhi(p0), aA1);
      aB0 = fmaf(w1, bflo(p1), aB0); aB1 = fmaf(w1, bfhi(p1), aB1);
      aA0 = fmaf(w2, bflo(p2), aA0); aA1 = fmaf(w2, bfhi(p2), aA1);
      aB0 = fmaf(w3, bflo(p3), aB0); aB1 = fmaf(w3, bfhi(p3), aB1);
      aA0 = fmaf(w4, bflo(p4), aA0); aA1 = fmaf(w4, bfhi(p4), aA1);
      aB0 = fmaf(w5, bflo(p5), aB0); aB1 = fmaf(w5, bfhi(p5), aB1);
      aA0 = fmaf(w6, bflo(p6), aA0); aA1 = fmaf(w6, bfhi(p6), aA1);
      aB0 = fmaf(w7, bflo(p7), aB0); aB1 = fmaf(w7, bfhi(p7), aB1);
    }
    float a0 = aA0 + aB0, a1 = aA1 + aB1;
    float dn = dinv[n];
    float sw = dn * dn;
    unsigned int pn = hpk[(size_t)n * 64 + lane];
    float o0 = fmaf(bflo(pn), sw, a0) + b0;
    float o1 = fmaf(bfhi(pn), sw, a1) + b1;
    outp[(size_t)n * 128 + lane] = o0;
    outp[(size_t)n * 128 + 64 + lane] = o1;
    s0 += o0; s1 += o1;
    q0 = fmaf(o0, o0, q0); q1 = fmaf(o1, o1, q1);
  }
  atomicAdd(&bnsum[lane], s0);
  atomicAdd(&bnsum[64 + lane], s1);
  atomicAdd(&bnsq[lane], q0);
  atomicAdd(&bnsq[64 + lane], q1);
}

// ---------------- fused dispatch: blocks [0,eb) edge-MLP, [eb,grid) SpMM ----------------
__global__ __launch_bounds__(256) void spmm_edge_kernel(const unsigned int* __restrict__ hpk,
                                                        const float* __restrict__ dinv,
                                                        const int* __restrict__ rp,
                                                        const int2* __restrict__ swv,
                                                        const float* __restrict__ bias,
                                                        float* __restrict__ outp,
                                                        float* __restrict__ bnsum,
                                                        float* __restrict__ bnsq, int nN,
                                                        const float* __restrict__ ea,
                                                        const unsigned int* __restrict__ epk,
                                                        const float* __restrict__ We1,
                                                        const float* __restrict__ be1,
                                                        float* __restrict__ esum,
                                                        float* __restrict__ ecnt,
                                                        int nE, int chunkE, int eb) {
  if ((int)blockIdx.x < eb) {
    edge_body(ea, epk, We1, be1, esum, ecnt, nE, chunkE);
  } else {
    spmm_body(hpk, dinv, rp, swv, bias, outp, bnsum, bnsq, nN, eb);
  }
}

// ---------------- BN finalize ----------------
__global__ void bnfin_kernel(const float* __restrict__ sum, const float* __restrict__ sq,
                             const float* __restrict__ gamma, const float* __restrict__ beta,
                             float* __restrict__ scale, float* __restrict__ shift,
                             float invN) {
  int c = threadIdx.x;
  float mu = sum[c] * invN;
  float var = sq[c] * invN - mu * mu;
  float sc = gamma[c] * rsqrtf(var + 1e-5f);
  scale[c] = sc;
  shift[c] = beta[c] - mu * sc;
}

// ---------------- graph mean pool, fused BN+ReLU ----------------
__global__ __launch_bounds__(256) void pool_kernel(const float* __restrict__ h,
                                                   const int* __restrict__ batch,
                                                   const float* __restrict__ scale,
                                                   const float* __restrict__ shift,
                                                   float* __restrict__ gsum,
                                                   float* __restrict__ gcnt,
                                                   int nN, int chunk) {
  const int lane = threadIdx.x & 63;
  const int wid = (blockIdx.x * blockDim.x + threadIdx.x) >> 6;
  int beg = wid * chunk;
  if (beg >= nN) return;
  int end = min(nN, beg + chunk);
  const int c2 = 2 * lane;
  float2 sc2 = *reinterpret_cast<const float2*>(scale + c2);
  float2 sh2 = *reinterpret_cast<const float2*>(shift + c2);
  int cur = -1;
  float a0 = 0.f, a1 = 0.f, cnt = 0.f;
  for (int n = beg; n < end; ++n) {
    int g = batch[n];
    if (g != cur) {
      if (cur >= 0) {
        atomicAdd(&gsum[cur * 128 + c2], a0);
        atomicAdd(&gsum[cur * 128 + c2 + 1], a1);
        if (lane == 0) atomicAdd(&gcnt[cur], cnt);
      }
      cur = g; a0 = 0.f; a1 = 0.f; cnt = 0.f;
    }
    float2 v = *reinterpret_cast<const float2*>(h + (size_t)n * 128 + c2);
    a0 += fmaxf(fmaf(v.x, sc2.x, sh2.x), 0.f);
    a1 += fmaxf(fmaf(v.y, sc2.y, sh2.y), 0.f);
    cnt += 1.f;
  }
  if (cur >= 0) {
    atomicAdd(&gsum[cur * 128 + c2], a0);
    atomicAdd(&gsum[cur * 128 + c2 + 1], a1);
    if (lane == 0) atomicAdd(&gcnt[cur], cnt);
  }
}

// ---------------- final: graph_repr + edge_repr ----------------
__global__ __launch_bounds__(128) void final_kernel(const float* __restrict__ gsum,
                                                    const float* __restrict__ gcnt,
                                                    const float* __restrict__ esum,
                                                    const float* __restrict__ ecnt,
                                                    const float* __restrict__ We2,
                                                    const float* __restrict__ be2,
                                                    float* __restrict__ out) {
  __shared__ float row[128];
  int g = blockIdx.x, c = threadIdx.x;
  row[c] = esum[g * 128 + c];
  __syncthreads();
  float acc = 0.f;
#pragma unroll 4
  for (int k = 0; k < 128; ++k) acc = fmaf(row[k], We2[k * 128 + c], acc);
  float ce = ecnt[g];
  float er = (ce > 0.f) ? (acc / ce + be2[c]) : 0.f;
  float cn = gcnt[g];
  float gr = gsum[g * 128 + c] / fmaxf(cn, 1.f);
  out[g * 128 + c] = gr + er;
}

extern "C" void kernel_launch(void* const* d_in, const int* in_sizes, int n_in,
                              void* d_out, int out_size, void* d_ws, size_t ws_size,
                              hipStream_t stream) {
  const float* x    = (const float*)d_in[0];
  const int*   ei   = (const int*)d_in[1];
  const float* ea   = (const float*)d_in[2];
  const int*   bidx = (const int*)d_in[3];
  const float* Wg1  = (const float*)d_in[4];
  const float* bg1  = (const float*)d_in[5];
  const float* gm1  = (const float*)d_in[6];
  const float* bt1  = (const float*)d_in[7];
  const float* Wg2  = (const float*)d_in[8];
  const float* bg2  = (const float*)d_in[9];
  const float* gm2  = (const float*)d_in[10];
  const float* bt2  = (const float*)d_in[11];
  const float* We1  = (const float*)d_in[12];
  const float* be1  = (const float*)d_in[13];
  const float* We2  = (const float*)d_in[14];
  const float* be2  = (const float*)d_in[15];
  float* out = (float*)d_out;

  const int N = in_sizes[3];
  const int E = in_sizes[1] / 2;
  const int G = out_size / 128;
  const int* srcp = ei;
  const int* dstp = ei + E;
  const int Epad = E + 8 * N;  // upper bound on padded CSR slots

  char* w = (char*)d_ws;
  auto alloc = [&](size_t b) {
    char* p = w;
    w += (b + 15) & ~(size_t)15;
    return p;
  };
  float* bufB    = (float*)alloc((size_t)N * 128 * 4);           // fp32 spmm output
  unsigned int* hpk = (unsigned int*)alloc((size_t)N * 64 * 4);  // packed bf16 h
  int2*  swv     = (int2*)alloc((size_t)Epad * 8);               // interleaved {src, wgt}
  unsigned int* epk = (unsigned int*)alloc((size_t)E * 4);
  int*   rp      = (int*)alloc((size_t)(N + 1) * 4);
  int*   rp2     = (int*)alloc((size_t)(N + 1) * 4);
  int*   cursor  = (int*)alloc((size_t)N * 4);
  int*   cursor2 = (int*)alloc((size_t)N * 4);
  float* dinv    = (float*)alloc((size_t)N * 4);
  char* zbase = w;
  int*   deg  = (int*)alloc((size_t)N * 4);
  int*   deg2 = (int*)alloc((size_t)N * 4);
  float* bs1  = (float*)alloc(512);
  float* bq1  = (float*)alloc(512);
  float* bs2  = (float*)alloc(512);
  float* bq2  = (float*)alloc(512);
  float* gsum = (float*)alloc((size_t)G * 128 * 4);
  float* gcnt = (float*)alloc((size_t)G * 4);
  float* esum = (float*)alloc((size_t)G * 128 * 4);
  float* ecnt = (float*)alloc((size_t)G * 4);
  int*   part  = (int*)alloc(4096);
  int*   part2 = (int*)alloc(4096);
  size_t zbytes = (size_t)(w - zbase);
  float* sc1 = (float*)alloc(512);
  float* sh1 = (float*)alloc(512);
  float* sc2 = (float*)alloc(512);
  float* sh2 = (float*)alloc(512);

  hipMemsetAsync(zbase, 0, zbytes, stream);

  (void)hipFuncSetAttribute((const void*)gemm128_kernel<false>,
                            hipFuncAttributeMaxDynamicSharedMemorySize, 73728);
  (void)hipFuncSetAttribute((const void*)gemm128_kernel<true>,
                            hipFuncAttributeMaxDynamicSharedMemorySize, 73728);

  // ---- prep: 5 kernels ----
  pre_kernel<<<(E + 255) / 256, 256, 0, stream>>>(srcp, dstp, deg, deg2, E);
  int nb = (N + 1023) / 1024;
  scanA_kernel<<<2 * nb, 256, 0, stream>>>(deg, deg2, rp, rp2, part, part2, N, nb);
  scanB_kernel<<<2, 64, 0, stream>>>(part, part2, rp, rp2, nb, N);
  scanC_kernel<<<(2 * N + 255) / 256, 256, 0, stream>>>(rp, rp2, part, part2, cursor,
                                                        cursor2, deg, dinv, N);
  placepad_kernel<<<(E + N + 255) / 256, 256, 0, stream>>>(srcp, dstp, bidx, dinv, cursor,
                                                           cursor2, swv, epk, rp, deg, E, N);

  const int EB = 512;                 // edge-MLP blocks co-scheduled with spmm1
  int nwe = EB * 4;
  int chunkE = (E + nwe - 1) / nwe;

  // layer 1 (edge path rides inside the spmm1 dispatch)
  gemm128_kernel<false><<<512, 256, 73728, stream>>>(x, Wg1, nullptr, nullptr, hpk, N);
  spmm_edge_kernel<<<EB + 2048, 256, 0, stream>>>(hpk, dinv, rp, swv, bg1, bufB, bs1, bq1, N,
                                                  ea, epk, We1, be1, esum, ecnt, E, chunkE, EB);
  bnfin_kernel<<<1, 128, 0, stream>>>(bs1, bq1, gm1, bt1, sc1, sh1, 1.0f / (float)N);

  // layer 2 (BN1+ReLU fused into GEMM2's A staging); eb=0 -> pure spmm
  gemm128_kernel<true><<<512, 256, 73728, stream>>>(bufB, Wg2, sc1, sh1, hpk, N);
  spmm_edge_kernel<<<2048, 256, 0, stream>>>(hpk, dinv, rp, swv, bg2, bufB, bs2, bq2, N,
                                             ea, epk, We1, be1, esum, ecnt, 0, 1, 0);
  bnfin_kernel<<<1, 128, 0, stream>>>(bs2, bq2, gm2, bt2, sc2, sh2, 1.0f / (float)N);

  // pooling (BN2+ReLU fused) + output
  int nwp = (2048 * 256) / 64;
  int chunkN = (N + nwp - 1) / nwp;
  pool_kernel<<<2048, 256, 0, stream>>>(bufB, bidx, sc2, sh2, gsum, gcnt, N, chunkN);
  final_kernel<<<G, 128, 0, stream>>>(gsum, gcnt, esum, ecnt, We2, be2, out);
}

// Round 8
// 1336.443 us; speedup vs baseline: 1.2995x; 1.2995x over previous
//
#include <hip/hip_runtime.h>
#include <cstdint>

// ---- bf16 pack/unpack helpers (RNE) ----
__device__ inline unsigned int bfpack2(float a, float b) {
  unsigned int ua = __float_as_uint(a), ub = __float_as_uint(b);
  ua += 0x7FFFu + ((ua >> 16) & 1u);
  ub += 0x7FFFu + ((ub >> 16) & 1u);
  return (ua >> 16) | (ub & 0xFFFF0000u);
}
__device__ inline float bflo(unsigned int u) { return __uint_as_float(u << 16); }
__device__ inline float bfhi(unsigned int u) { return __uint_as_float(u & 0xFFFF0000u); }

// ---------------- degree histograms ----------------
__global__ __launch_bounds__(256) void pre_kernel(const int* __restrict__ src,
                                                  const int* __restrict__ dst,
                                                  int* __restrict__ deg,
                                                  int* __restrict__ deg2, int nE) {
  int e = blockIdx.x * 256 + threadIdx.x;
  if (e < nE) {
    atomicAdd(&deg[dst[e]], 1);
    atomicAdd(&deg2[src[e]], 1);
  }
}

// ---------------- scan stage A ----------------
__global__ __launch_bounds__(256) void scanA_kernel(const int* __restrict__ deg,
                                                    const int* __restrict__ deg2,
                                                    int* __restrict__ rp,
                                                    int* __restrict__ rp2,
                                                    int* __restrict__ part,
                                                    int* __restrict__ part2,
                                                    int n, int nb) {
  __shared__ int sh[256];
  int b = blockIdx.x, t = threadIdx.x;
  const int* d = (b < nb) ? deg : deg2;
  int* r = (b < nb) ? rp : rp2;
  int* p = (b < nb) ? part : part2;
  int pad = (b < nb) ? 1 : 0;
  int bb = (b < nb) ? b : b - nb;
  int base = bb * 1024 + t * 4;
  int v0 = (base + 0 < n) ? d[base + 0] : 0;
  int v1 = (base + 1 < n) ? d[base + 1] : 0;
  int v2 = (base + 2 < n) ? d[base + 2] : 0;
  int v3 = (base + 3 < n) ? d[base + 3] : 0;
  if (pad) {
    v0 = (v0 + 7) & ~7; v1 = (v1 + 7) & ~7;
    v2 = (v2 + 7) & ~7; v3 = (v3 + 7) & ~7;
  }
  int ts = v0 + v1 + v2 + v3;
  sh[t] = ts;
  __syncthreads();
  for (int off = 1; off < 256; off <<= 1) {
    int x = (t >= off) ? sh[t - off] : 0;
    __syncthreads();
    sh[t] += x;
    __syncthreads();
  }
  int excl = sh[t] - ts;
  if (t == 255) p[bb] = sh[255];
  if (base + 0 < n) r[base + 0] = excl;
  if (base + 1 < n) r[base + 1] = excl + v0;
  if (base + 2 < n) r[base + 2] = excl + v0 + v1;
  if (base + 3 < n) r[base + 3] = excl + v0 + v1 + v2;
}

// ---------------- scan stage B ----------------
__global__ void scanB_kernel(int* part, int* part2, int* rp, int* rp2, int nb, int n) {
  if (threadIdx.x == 0) {
    int* p = (blockIdx.x == 0) ? part : part2;
    int* r = (blockIdx.x == 0) ? rp : rp2;
    int run = 0;
    for (int i = 0; i < nb; ++i) { int v = p[i]; p[i] = run; run += v; }
    r[n] = run;
  }
}

// ---------------- scan stage C ----------------
__global__ __launch_bounds__(256) void scanC_kernel(int* __restrict__ rp,
                                                    int* __restrict__ rp2,
                                                    const int* __restrict__ part,
                                                    const int* __restrict__ part2,
                                                    int* __restrict__ cursor,
                                                    int* __restrict__ cursor2,
                                                    const int* __restrict__ deg,
                                                    float* __restrict__ dinv, int n) {
  int i = blockIdx.x * 256 + threadIdx.x;
  if (i < n) {
    int v = rp[i] + part[i >> 10];
    rp[i] = v;
    cursor[i] = v;
    dinv[i] = rsqrtf((float)deg[i] + 1.0f);
  } else if (i < 2 * n) {
    int j = i - n;
    int v = rp2[j] + part2[j >> 10];
    rp2[j] = v;
    cursor2[j] = v;
  }
}

// ---------------- place + pad fused ----------------
__global__ __launch_bounds__(256) void placepad_kernel(const int* __restrict__ src,
                                                       const int* __restrict__ dst,
                                                       const int* __restrict__ batch,
                                                       const float* __restrict__ dinv,
                                                       int* __restrict__ cursor,
                                                       int* __restrict__ cursor2,
                                                       int2* __restrict__ swv,
                                                       unsigned int* __restrict__ epk,
                                                       const int* __restrict__ rp,
                                                       const int* __restrict__ deg,
                                                       int nE, int nN) {
  int t = blockIdx.x * 256 + threadIdx.x;
  if (t < nE) {
    int s = src[t];
    int d = dst[t];
    int p1 = atomicAdd(&cursor[d], 1);
    int2 sw; sw.x = s; sw.y = __float_as_int(dinv[s] * dinv[d]);
    swv[p1] = sw;
    int g = batch[s];
    int p2 = atomicAdd(&cursor2[s], 1);
    epk[p2] = ((unsigned int)g << 21) | (unsigned int)t;
  } else if (t < nE + nN) {
    int i = t - nE;
    int b = rp[i] + deg[i], e = rp[i + 1];
    int2 z; z.x = i; z.y = 0;
    for (int k = b; k < e; ++k) swv[k] = z;
  }
}

// ---------------- dense GEMM: hpk2[8][N][8] = pack_bf16(act(A) @ W), slice-major ----------------
// Slice s holds u32 entries [8s,8s+8) of each row (channels c and c+64 packed per entry).
// Slice-major layout keeps each XCD's SpMM working set contiguous (3.2 MB < 4 MiB L2).
template <bool FUSED>
__global__ __launch_bounds__(256) void gemm128_kernel(const float* __restrict__ A,
                                                      const float* __restrict__ W,
                                                      const float* __restrict__ scale,
                                                      const float* __restrict__ shift,
                                                      unsigned int* __restrict__ hpk2,
                                                      int nrows) {
  extern __shared__ float lds[];
  float* Ws = lds;             // 128*128 floats
  float* xs = lds + 128 * 128; // 16*128 floats
  const int t = threadIdx.x;
  for (int i = t; i < (128 * 128) / 4; i += 256)
    reinterpret_cast<float4*>(Ws)[i] = reinterpret_cast<const float4*>(W)[i];
  const int wave = t >> 6, lane = t & 63;
  const size_t sbase = (size_t)(lane >> 3) * (size_t)nrows * 8 + (lane & 7);
  for (int rb = blockIdx.x * 16; rb < nrows; rb += gridDim.x * 16) {
    int nr = min(16, nrows - rb);
    __syncthreads();
    for (int i = t; i < nr * 32; i += 256) {
      float4 v = reinterpret_cast<const float4*>(A + (size_t)rb * 128)[i];
      if (FUSED) {
        float4 sc4 = reinterpret_cast<const float4*>(scale)[i & 31];
        float4 sh4 = reinterpret_cast<const float4*>(shift)[i & 31];
        v.x = fmaxf(fmaf(v.x, sc4.x, sh4.x), 0.f);
        v.y = fmaxf(fmaf(v.y, sc4.y, sh4.y), 0.f);
        v.z = fmaxf(fmaf(v.z, sc4.z, sh4.z), 0.f);
        v.w = fmaxf(fmaf(v.w, sc4.w, sh4.w), 0.f);
      }
      reinterpret_cast<float4*>(xs)[i] = v;
    }
    __syncthreads();
    float acc[4][2] = {{0.f, 0.f}, {0.f, 0.f}, {0.f, 0.f}, {0.f, 0.f}};
    const float* xw = xs + wave * 4 * 128;
#pragma unroll 4
    for (int k = 0; k < 128; ++k) {
      float w0 = Ws[k * 128 + lane];
      float w1 = Ws[k * 128 + 64 + lane];
#pragma unroll
      for (int r = 0; r < 4; ++r) {
        float a = xw[r * 128 + k];
        acc[r][0] = fmaf(a, w0, acc[r][0]);
        acc[r][1] = fmaf(a, w1, acc[r][1]);
      }
    }
#pragma unroll
    for (int r = 0; r < 4; ++r) {
      int row = rb + wave * 4 + r;
      if (row < nrows)
        hpk2[sbase + (size_t)row * 8] = bfpack2(acc[r][0], acc[r][1]);
    }
  }
}

// ---------------- SpMM, XCD channel-sliced ----------------
// Block's slice = blockIdx%8 (XCD round-robin) -> this block only touches
// hpk2 slice [slice][N][8] (3.2 MB, L2-resident). Wave = node; lane = es*8+ch:
// 8 edges x 8 channels per iteration (32B contiguous per edge), x2 unroll ->
// 16 row-chunks in flight. Node reduce = 3 shfl_xor. swv nt-loaded, outp
// nt-stored to keep the hpk2 slice resident.
__global__ __launch_bounds__(256) void spmm8_kernel(const unsigned int* __restrict__ hpk2,
                                                    const float* __restrict__ dinv,
                                                    const int* __restrict__ rp,
                                                    const int2* __restrict__ swv,
                                                    const float* __restrict__ bias,
                                                    float* __restrict__ outp,
                                                    float* __restrict__ bnsum,
                                                    float* __restrict__ bnsq, int nN) {
  const int lane = threadIdx.x & 63;
  const int ch = lane & 7;
  const int es = lane >> 3;
  const int slice = blockIdx.x & 7;
  const unsigned int* hs = hpk2 + (size_t)slice * (size_t)nN * 8;
  const int cb = slice * 8;
  const int wib = (int)(blockIdx.x >> 3) * 4 + (int)(threadIdx.x >> 6);
  const int nws = (int)(gridDim.x >> 3) * 4;
  const unsigned long long* swq = reinterpret_cast<const unsigned long long*>(swv);
  float b0 = bias[cb + ch], b1 = bias[64 + cb + ch];
  float s0 = 0.f, s1 = 0.f, q0 = 0.f, q1 = 0.f;
  for (int n = wib; n < nN; n += nws) {
    const int beg = rp[n], end = rp[n + 1];
    float a0 = 0.f, a1 = 0.f, c0 = 0.f, c1 = 0.f;
    int j = beg;
    for (; j + 8 < end; j += 16) {
      unsigned long long v0 = __builtin_nontemporal_load(swq + j + es);
      unsigned long long v1 = __builtin_nontemporal_load(swq + j + 8 + es);
      int sA = (int)(unsigned int)v0;
      int sB = (int)(unsigned int)v1;
      float wA = __uint_as_float((unsigned int)(v0 >> 32));
      float wB = __uint_as_float((unsigned int)(v1 >> 32));
      unsigned int pA = hs[(size_t)sA * 8 + ch];
      unsigned int pB = hs[(size_t)sB * 8 + ch];
      a0 = fmaf(wA, bflo(pA), a0); a1 = fmaf(wA, bfhi(pA), a1);
      c0 = fmaf(wB, bflo(pB), c0); c1 = fmaf(wB, bfhi(pB), c1);
    }
    if (j < end) {
      unsigned long long v0 = __builtin_nontemporal_load(swq + j + es);
      int sA = (int)(unsigned int)v0;
      float wA = __uint_as_float((unsigned int)(v0 >> 32));
      unsigned int pA = hs[(size_t)sA * 8 + ch];
      a0 = fmaf(wA, bflo(pA), a0); a1 = fmaf(wA, bfhi(pA), a1);
    }
    a0 += c0; a1 += c1;
    a0 += __shfl_xor(a0, 8);  a1 += __shfl_xor(a1, 8);
    a0 += __shfl_xor(a0, 16); a1 += __shfl_xor(a1, 16);
    a0 += __shfl_xor(a0, 32); a1 += __shfl_xor(a1, 32);
    if (es == 0) {
      float dn = dinv[n];
      float sw = dn * dn;
      unsigned int pn = hs[(size_t)n * 8 + ch];
      float o0 = fmaf(bflo(pn), sw, a0) + b0;
      float o1 = fmaf(bfhi(pn), sw, a1) + b1;
      __builtin_nontemporal_store(o0, &outp[(size_t)n * 128 + cb + ch]);
      __builtin_nontemporal_store(o1, &outp[(size_t)n * 128 + 64 + cb + ch]);
      s0 += o0; s1 += o1;
      q0 = fmaf(o0, o0, q0); q1 = fmaf(o1, o1, q1);
    }
  }
  if (es == 0) {
    atomicAdd(&bnsum[cb + ch], s0);
    atomicAdd(&bnsum[64 + cb + ch], s1);
    atomicAdd(&bnsq[cb + ch], q0);
    atomicAdd(&bnsq[64 + cb + ch], q1);
  }
}

// ---------------- BN finalize ----------------
__global__ void bnfin_kernel(const float* __restrict__ sum, const float* __restrict__ sq,
                             const float* __restrict__ gamma, const float* __restrict__ beta,
                             float* __restrict__ scale, float* __restrict__ shift,
                             float invN) {
  int c = threadIdx.x;
  float mu = sum[c] * invN;
  float var = sq[c] * invN - mu * mu;
  float sc = gamma[c] * rsqrtf(var + 1e-5f);
  scale[c] = sc;
  shift[c] = beta[c] - mu * sc;
}

// ---------------- graph mean pool, fused BN+ReLU ----------------
__global__ __launch_bounds__(256) void pool_kernel(const float* __restrict__ h,
                                                   const int* __restrict__ batch,
                                                   const float* __restrict__ scale,
                                                   const float* __restrict__ shift,
                                                   float* __restrict__ gsum,
                                                   float* __restrict__ gcnt,
                                                   int nN, int chunk) {
  const int lane = threadIdx.x & 63;
  const int wid = (blockIdx.x * blockDim.x + threadIdx.x) >> 6;
  int beg = wid * chunk;
  if (beg >= nN) return;
  int end = min(nN, beg + chunk);
  const int c2 = 2 * lane;
  float2 sc2 = *reinterpret_cast<const float2*>(scale + c2);
  float2 sh2 = *reinterpret_cast<const float2*>(shift + c2);
  int cur = -1;
  float a0 = 0.f, a1 = 0.f, cnt = 0.f;
  for (int n = beg; n < end; ++n) {
    int g = batch[n];
    if (g != cur) {
      if (cur >= 0) {
        atomicAdd(&gsum[cur * 128 + c2], a0);
        atomicAdd(&gsum[cur * 128 + c2 + 1], a1);
        if (lane == 0) atomicAdd(&gcnt[cur], cnt);
      }
      cur = g; a0 = 0.f; a1 = 0.f; cnt = 0.f;
    }
    float2 v = *reinterpret_cast<const float2*>(h + (size_t)n * 128 + c2);
    a0 += fmaxf(fmaf(v.x, sc2.x, sh2.x), 0.f);
    a1 += fmaxf(fmaf(v.y, sc2.y, sh2.y), 0.f);
    cnt += 1.f;
  }
  if (cur >= 0) {
    atomicAdd(&gsum[cur * 128 + c2], a0);
    atomicAdd(&gsum[cur * 128 + c2 + 1], a1);
    if (lane == 0) atomicAdd(&gcnt[cur], cnt);
  }
}

// ---------------- edge MLP layer1 + per-graph sum (separate dispatch) ----------------
__global__ __launch_bounds__(256) void edge2_kernel(const float* __restrict__ ea,
                                                    const unsigned int* __restrict__ epk,
                                                    const float* __restrict__ We1,
                                                    const float* __restrict__ be1,
                                                    float* __restrict__ esum,
                                                    float* __restrict__ ecnt,
                                                    int nE, int chunk) {
  const int lane = threadIdx.x & 63;
  const int wid = (blockIdx.x * 256 + threadIdx.x) >> 6;
  int beg = wid * chunk;
  if (beg >= nE) return;
  int end = min(nE, beg + chunk);
  float w0[16], w1[16];
#pragma unroll
  for (int k = 0; k < 16; ++k) {
    w0[k] = We1[k * 128 + lane];
    w1[k] = We1[k * 128 + 64 + lane];
  }
  float b0 = be1[lane], b1 = be1[64 + lane];
  int cur = -1;
  float a0 = 0.f, a1 = 0.f, cnt = 0.f;
  for (int j = beg; j < end; ++j) {
    unsigned int pk = epk[j];
    int g = (int)(pk >> 21);
    int e = (int)(pk & 0x1FFFFFu);
    if (g != cur) {
      if (cur >= 0) {
        atomicAdd(&esum[cur * 128 + lane], a0);
        atomicAdd(&esum[cur * 128 + 64 + lane], a1);
        if (lane == 0) atomicAdd(&ecnt[cur], cnt);
      }
      cur = g; a0 = 0.f; a1 = 0.f; cnt = 0.f;
    }
    const float4* eap = reinterpret_cast<const float4*>(ea + (size_t)e * 16);
    float4 t0 = eap[0], t1 = eap[1], t2 = eap[2], t3 = eap[3];
    float u0 = b0, u1 = b1;
    u0 = fmaf(t0.x, w0[0], u0);  u1 = fmaf(t0.x, w1[0], u1);
    u0 = fmaf(t0.y, w0[1], u0);  u1 = fmaf(t0.y, w1[1], u1);
    u0 = fmaf(t0.z, w0[2], u0);  u1 = fmaf(t0.z, w1[2], u1);
    u0 = fmaf(t0.w, w0[3], u0);  u1 = fmaf(t0.w, w1[3], u1);
    u0 = fmaf(t1.x, w0[4], u0);  u1 = fmaf(t1.x, w1[4], u1);
    u0 = fmaf(t1.y, w0[5], u0);  u1 = fmaf(t1.y, w1[5], u1);
    u0 = fmaf(t1.z, w0[6], u0);  u1 = fmaf(t1.z, w1[6], u1);
    u0 = fmaf(t1.w, w0[7], u0);  u1 = fmaf(t1.w, w1[7], u1);
    u0 = fmaf(t2.x, w0[8], u0);  u1 = fmaf(t2.x, w1[8], u1);
    u0 = fmaf(t2.y, w0[9], u0);  u1 = fmaf(t2.y, w1[9], u1);
    u0 = fmaf(t2.z, w0[10], u0); u1 = fmaf(t2.z, w1[10], u1);
    u0 = fmaf(t2.w, w0[11], u0); u1 = fmaf(t2.w, w1[11], u1);
    u0 = fmaf(t3.x, w0[12], u0); u1 = fmaf(t3.x, w1[12], u1);
    u0 = fmaf(t3.y, w0[13], u0); u1 = fmaf(t3.y, w1[13], u1);
    u0 = fmaf(t3.z, w0[14], u0); u1 = fmaf(t3.z, w1[14], u1);
    u0 = fmaf(t3.w, w0[15], u0); u1 = fmaf(t3.w, w1[15], u1);
    a0 += fmaxf(u0, 0.f);
    a1 += fmaxf(u1, 0.f);
    cnt += 1.f;
  }
  if (cur >= 0) {
    atomicAdd(&esum[cur * 128 + lane], a0);
    atomicAdd(&esum[cur * 128 + 64 + lane], a1);
    if (lane == 0) atomicAdd(&ecnt[cur], cnt);
  }
}

// ---------------- final: graph_repr + edge_repr ----------------
__global__ __launch_bounds__(128) void final_kernel(const float* __restrict__ gsum,
                                                    const float* __restrict__ gcnt,
                                                    const float* __restrict__ esum,
                                                    const float* __restrict__ ecnt,
                                                    const float* __restrict__ We2,
                                                    const float* __restrict__ be2,
                                                    float* __restrict__ out) {
  __shared__ float row[128];
  int g = blockIdx.x, c = threadIdx.x;
  row[c] = esum[g * 128 + c];
  __syncthreads();
  float acc = 0.f;
#pragma unroll 4
  for (int k = 0; k < 128; ++k) acc = fmaf(row[k], We2[k * 128 + c], acc);
  float ce = ecnt[g];
  float er = (ce > 0.f) ? (acc / ce + be2[c]) : 0.f;
  float cn = gcnt[g];
  float gr = gsum[g * 128 + c] / fmaxf(cn, 1.f);
  out[g * 128 + c] = gr + er;
}

extern "C" void kernel_launch(void* const* d_in, const int* in_sizes, int n_in,
                              void* d_out, int out_size, void* d_ws, size_t ws_size,
                              hipStream_t stream) {
  const float* x    = (const float*)d_in[0];
  const int*   ei   = (const int*)d_in[1];
  const float* ea   = (const float*)d_in[2];
  const int*   bidx = (const int*)d_in[3];
  const float* Wg1  = (const float*)d_in[4];
  const float* bg1  = (const float*)d_in[5];
  const float* gm1  = (const float*)d_in[6];
  const float* bt1  = (const float*)d_in[7];
  const float* Wg2  = (const float*)d_in[8];
  const float* bg2  = (const float*)d_in[9];
  const float* gm2  = (const float*)d_in[10];
  const float* bt2  = (const float*)d_in[11];
  const float* We1  = (const float*)d_in[12];
  const float* be1  = (const float*)d_in[13];
  const float* We2  = (const float*)d_in[14];
  const float* be2  = (const float*)d_in[15];
  float* out = (float*)d_out;

  const int N = in_sizes[3];
  const int E = in_sizes[1] / 2;
  const int G = out_size / 128;
  const int* srcp = ei;
  const int* dstp = ei + E;
  const int Epad = E + 8 * N;

  char* w = (char*)d_ws;
  auto alloc = [&](size_t b) {
    char* p = w;
    w += (b + 15) & ~(size_t)15;
    return p;
  };
  float* bufB    = (float*)alloc((size_t)N * 128 * 4);            // fp32 spmm output
  unsigned int* hpk2 = (unsigned int*)alloc((size_t)N * 64 * 4);  // packed bf16 h, slice-major [8][N][8]
  int2*  swv     = (int2*)alloc((size_t)Epad * 8);                // interleaved {src, wgt}
  unsigned int* epk = (unsigned int*)alloc((size_t)E * 4);
  int*   rp      = (int*)alloc((size_t)(N + 1) * 4);
  int*   rp2     = (int*)alloc((size_t)(N + 1) * 4);
  int*   cursor  = (int*)alloc((size_t)N * 4);
  int*   cursor2 = (int*)alloc((size_t)N * 4);
  float* dinv    = (float*)alloc((size_t)N * 4);
  char* zbase = w;
  int*   deg  = (int*)alloc((size_t)N * 4);
  int*   deg2 = (int*)alloc((size_t)N * 4);
  float* bs1  = (float*)alloc(512);
  float* bq1  = (float*)alloc(512);
  float* bs2  = (float*)alloc(512);
  float* bq2  = (float*)alloc(512);
  float* gsum = (float*)alloc((size_t)G * 128 * 4);
  float* gcnt = (float*)alloc((size_t)G * 4);
  float* esum = (float*)alloc((size_t)G * 128 * 4);
  float* ecnt = (float*)alloc((size_t)G * 4);
  int*   part  = (int*)alloc(4096);
  int*   part2 = (int*)alloc(4096);
  size_t zbytes = (size_t)(w - zbase);
  float* sc1 = (float*)alloc(512);
  float* sh1 = (float*)alloc(512);
  float* sc2 = (float*)alloc(512);
  float* sh2 = (float*)alloc(512);

  hipMemsetAsync(zbase, 0, zbytes, stream);

  (void)hipFuncSetAttribute((const void*)gemm128_kernel<false>,
                            hipFuncAttributeMaxDynamicSharedMemorySize, 73728);
  (void)hipFuncSetAttribute((const void*)gemm128_kernel<true>,
                            hipFuncAttributeMaxDynamicSharedMemorySize, 73728);

  // ---- prep: 5 kernels ----
  pre_kernel<<<(E + 255) / 256, 256, 0, stream>>>(srcp, dstp, deg, deg2, E);
  int nb = (N + 1023) / 1024;
  scanA_kernel<<<2 * nb, 256, 0, stream>>>(deg, deg2, rp, rp2, part, part2, N, nb);
  scanB_kernel<<<2, 64, 0, stream>>>(part, part2, rp, rp2, nb, N);
  scanC_kernel<<<(2 * N + 255) / 256, 256, 0, stream>>>(rp, rp2, part, part2, cursor,
                                                        cursor2, deg, dinv, N);
  placepad_kernel<<<(E + N + 255) / 256, 256, 0, stream>>>(srcp, dstp, bidx, dinv, cursor,
                                                           cursor2, swv, epk, rp, deg, E, N);

  // layer 1
  gemm128_kernel<false><<<512, 256, 73728, stream>>>(x, Wg1, nullptr, nullptr, hpk2, N);
  spmm8_kernel<<<2048, 256, 0, stream>>>(hpk2, dinv, rp, swv, bg1, bufB, bs1, bq1, N);
  bnfin_kernel<<<1, 128, 0, stream>>>(bs1, bq1, gm1, bt1, sc1, sh1, 1.0f / (float)N);

  // layer 2 (BN1+ReLU fused into GEMM2's A staging)
  gemm128_kernel<true><<<512, 256, 73728, stream>>>(bufB, Wg2, sc1, sh1, hpk2, N);
  spmm8_kernel<<<2048, 256, 0, stream>>>(hpk2, dinv, rp, swv, bg2, bufB, bs2, bq2, N);
  bnfin_kernel<<<1, 128, 0, stream>>>(bs2, bq2, gm2, bt2, sc2, sh2, 1.0f / (float)N);

  // pooling (BN2+ReLU fused) + edge path + output
  int nwp = (2048 * 256) / 64;
  int chunkN = (N + nwp - 1) / nwp;
  pool_kernel<<<2048, 256, 0, stream>>>(bufB, bidx, sc2, sh2, gsum, gcnt, N, chunkN);
  int nwe = (2048 * 256) / 64;
  int chunkE = (E + nwe - 1) / nwe;
  edge2_kernel<<<2048, 256, 0, stream>>>(ea, epk, We1, be1, esum, ecnt, E, chunkE);
  final_kernel<<<G, 128, 0, stream>>>(gsum, gcnt, esum, ecnt, We2, be2, out);
}